// Round 6
// baseline (67.691 us; speedup 1.0000x reference)
//
#include <hip/hip_runtime.h>

#define SEQ 2048
#define DIM 6
#define BLOCK 256
#define RROWS 4  // query rows per thread

typedef __fp16 half8 __attribute__((ext_vector_type(8)));
typedef __fp16 half2v __attribute__((ext_vector_type(2)));
typedef float f32x2 __attribute__((ext_vector_type(2)));

union H8 {
    half8 v8;
    half2v h2[4];
};

__device__ __forceinline__ float fdot2_(half2v a, half2v b, float c) {
#if __has_builtin(__builtin_amdgcn_fdot2)
    return __builtin_amdgcn_fdot2(a, b, c, false);
#else
    return fmaf((float)a[0], (float)b[0], fmaf((float)a[1], (float)b[1], c));
#endif
}

__device__ __forceinline__ f32x2 pk_fma_(f32x2 a, f32x2 b, f32x2 c) {
#if __has_builtin(__builtin_elementwise_fma)
    return __builtin_elementwise_fma(a, b, c);  // -> v_pk_fma_f32
#else
    return (f32x2){fmaf(a[0], b[0], c[0]), fmaf(a[1], b[1], c[1])};
#endif
}

// K' row [chunk][8] fp16: {k0..k5 (scaled by log2 e), bias (0 or -1024), 0}
// Vp    [chunk/2][16] fp16: dim d -> (v_t[d], v_{t+1}[d]); slots 6,7 unused
// partials [B][T][SEQ][8] f32: {num0..num5, denom, pad}

__launch_bounds__(BLOCK, 4)
__global__ void attn_partial(const float* __restrict__ X,
                             const int* __restrict__ mask,
                             const float* __restrict__ Wq, const float* __restrict__ bq,
                             const float* __restrict__ Wk, const float* __restrict__ bk,
                             const float* __restrict__ Wv, const float* __restrict__ bv,
                             float* __restrict__ partials,
                             int T, int chunk) {
    extern __shared__ __fp16 smem[];
    __fp16* Ksm = smem;               // [chunk][8] fp16
    __fp16* Vpsm = smem + chunk * 8;  // [chunk/2][16] fp16 (8 half2)

    const int rc = blockIdx.x;
    const int tc = blockIdx.y;
    const int b  = blockIdx.z;
    const int tid = threadIdx.x;

    const float* Xb = X + (size_t)b * SEQ * DIM;
    const int* mb = mask + (size_t)b * SEQ;
    const float L2E = 1.44269504088896f;

    // ---- Stage K' (fp16) and pair-interleaved V' into LDS ----
    for (int j = tid; j < (chunk >> 1); j += BLOCK) {
        float vrow[2][DIM];
#pragma unroll
        for (int h = 0; h < 2; ++h) {
            const int tg = tc * chunk + 2 * j + h;
            const float2* xp = reinterpret_cast<const float2*>(Xb + tg * DIM);
            float2 x01 = xp[0], x23 = xp[1], x45 = xp[2];
            float x[DIM] = {x01.x, x01.y, x23.x, x23.y, x45.x, x45.y};
            H8 ks;
#pragma unroll
            for (int i = 0; i < DIM; ++i) {
                float kk = bk[i];
                float vv = bv[i];
#pragma unroll
                for (int jj = 0; jj < DIM; ++jj) {
                    kk = fmaf(Wk[i * DIM + jj], x[jj], kk);
                    vv = fmaf(Wv[i * DIM + jj], x[jj], vv);
                }
                ks.v8[i] = (__fp16)(kk * L2E);
                vrow[h][i] = vv;
            }
            ks.v8[6] = (mb[tg] == 0) ? (__fp16)(-1024.0f) : (__fp16)0.0f;
            ks.v8[7] = (__fp16)0.0f;
            *reinterpret_cast<half8*>(&Ksm[(2 * j + h) * 8]) = ks.v8;
        }
        H8 vp0, vp1;
#pragma unroll
        for (int i = 0; i < 4; ++i)
            vp0.h2[i] = __builtin_amdgcn_cvt_pkrtz(vrow[0][i], vrow[1][i]);
        vp1.h2[0] = __builtin_amdgcn_cvt_pkrtz(vrow[0][4], vrow[1][4]);
        vp1.h2[1] = __builtin_amdgcn_cvt_pkrtz(vrow[0][5], vrow[1][5]);
        vp1.h2[2] = __builtin_amdgcn_cvt_pkrtz(0.0f, 0.0f);
        vp1.h2[3] = __builtin_amdgcn_cvt_pkrtz(0.0f, 0.0f);
        *reinterpret_cast<half8*>(&Vpsm[j * 16]) = vp0.v8;
        *reinterpret_cast<half8*>(&Vpsm[j * 16 + 8]) = vp1.v8;
    }
    __syncthreads();

    // ---- Project q (fp16 pairs) for RROWS rows owned by this thread ----
    half2v qh[RROWS][4];
    int rows[RROWS];
#pragma unroll
    for (int k = 0; k < RROWS; ++k) {
        const int s = rc * (BLOCK * RROWS) + k * BLOCK + tid;
        rows[k] = s;
        const float2* xp = reinterpret_cast<const float2*>(Xb + s * DIM);
        float2 x01 = xp[0], x23 = xp[1], x45 = xp[2];
        float x[DIM] = {x01.x, x01.y, x23.x, x23.y, x45.x, x45.y};
        const bool rm = (mb[s] == 0);  // masked row -> p=1 over all t
        float qq[DIM];
#pragma unroll
        for (int i = 0; i < DIM; ++i) {
            float t = bq[i];
#pragma unroll
            for (int j = 0; j < DIM; ++j) t = fmaf(Wq[i * DIM + j], x[j], t);
            qq[i] = rm ? 0.0f : t;
        }
        qh[k][0] = __builtin_amdgcn_cvt_pkrtz(qq[0], qq[1]);
        qh[k][1] = __builtin_amdgcn_cvt_pkrtz(qq[2], qq[3]);
        qh[k][2] = __builtin_amdgcn_cvt_pkrtz(qq[4], qq[5]);
        qh[k][3] = __builtin_amdgcn_cvt_pkrtz(rm ? 0.0f : 1.0f, 0.0f);  // bias mult
    }

    // Packed accumulators: acc2[k][d] = (num_d from even t, num_d from odd t);
    // acc2[k][6] = packed denominator.
    f32x2 acc2[RROWS][7];
#pragma unroll
    for (int k = 0; k < RROWS; ++k)
#pragma unroll
        for (int i = 0; i < 7; ++i) acc2[k][i] = (f32x2){0.0f, 0.0f};

    const f32x2 ones = {1.0f, 1.0f};

    // ---- Stream step pairs ----
    const int npair = chunk >> 1;
#pragma unroll 2
    for (int j = 0; j < npair; ++j) {
        H8 k0, k1, vp0, vp1;
        k0.v8 = *reinterpret_cast<const half8*>(&Ksm[(2 * j) * 8]);
        k1.v8 = *reinterpret_cast<const half8*>(&Ksm[(2 * j + 1) * 8]);
        vp0.v8 = *reinterpret_cast<const half8*>(&Vpsm[j * 16]);
        vp1.v8 = *reinterpret_cast<const half8*>(&Vpsm[j * 16 + 8]);
        // Convert V pairs to f32 once, shared across RROWS rows.
        f32x2 v01[DIM];
#pragma unroll
        for (int d = 0; d < 4; ++d)
            v01[d] = (f32x2){(float)vp0.h2[d][0], (float)vp0.h2[d][1]};
        v01[4] = (f32x2){(float)vp1.h2[0][0], (float)vp1.h2[0][1]};
        v01[5] = (f32x2){(float)vp1.h2[1][0], (float)vp1.h2[1][1]};
#pragma unroll
        for (int k = 0; k < RROWS; ++k) {
            float a0 = fdot2_(qh[k][0], k0.h2[0], 0.0f);
            a0 = fdot2_(qh[k][1], k0.h2[1], a0);
            a0 = fdot2_(qh[k][2], k0.h2[2], a0);
            a0 = fdot2_(qh[k][3], k0.h2[3], a0);
            float a1 = fdot2_(qh[k][0], k1.h2[0], 0.0f);
            a1 = fdot2_(qh[k][1], k1.h2[1], a1);
            a1 = fdot2_(qh[k][2], k1.h2[2], a1);
            a1 = fdot2_(qh[k][3], k1.h2[3], a1);
            const f32x2 p01 = {__builtin_amdgcn_exp2f(a0),
                               __builtin_amdgcn_exp2f(a1)};
#pragma unroll
            for (int d = 0; d < DIM; ++d)
                acc2[k][d] = pk_fma_(p01, v01[d], acc2[k][d]);  // v_pk_fma_f32
            acc2[k][6] = pk_fma_(p01, ones, acc2[k][6]);        // denom
        }
    }

    // ---- Write partials (horizontal add of packed accumulators) ----
#pragma unroll
    for (int k = 0; k < RROWS; ++k) {
        float* pp = partials + ((((size_t)b * T + tc) * SEQ) + rows[k]) * 8;
        *reinterpret_cast<float4*>(pp) =
            make_float4(acc2[k][0][0] + acc2[k][0][1],
                        acc2[k][1][0] + acc2[k][1][1],
                        acc2[k][2][0] + acc2[k][2][1],
                        acc2[k][3][0] + acc2[k][3][1]);
        *reinterpret_cast<float4*>(pp + 4) =
            make_float4(acc2[k][4][0] + acc2[k][4][1],
                        acc2[k][5][0] + acc2[k][5][1],
                        acc2[k][6][0] + acc2[k][6][1], 0.0f);
    }
}

__launch_bounds__(BLOCK)
__global__ void attn_reduce(const float* __restrict__ partials,
                            float* __restrict__ out, int T) {
    const int idx = blockIdx.x * BLOCK + threadIdx.x;  // (b, s) flattened
    const int b = idx >> 11;
    const int s = idx & (SEQ - 1);
    float acc[7] = {0, 0, 0, 0, 0, 0, 0};
    for (int tc = 0; tc < T; ++tc) {
        const float4* pp = reinterpret_cast<const float4*>(
            partials + ((((size_t)b * T + tc) * SEQ) + s) * 8);
        float4 a0 = pp[0], a1 = pp[1];
        acc[0] += a0.x; acc[1] += a0.y; acc[2] += a0.z; acc[3] += a0.w;
        acc[4] += a1.x; acc[5] += a1.y; acc[6] += a1.z;
    }
    const float inv = 1.0f / acc[6];
    float* o = out + (size_t)idx * DIM;
    float2* o2 = reinterpret_cast<float2*>(o);
    o2[0] = make_float2(acc[0] * inv, acc[1] * inv);
    o2[1] = make_float2(acc[2] * inv, acc[3] * inv);
    o2[2] = make_float2(acc[4] * inv, acc[5] * inv);
}

extern "C" void kernel_launch(void* const* d_in, const int* in_sizes, int n_in,
                              void* d_out, int out_size, void* d_ws, size_t ws_size,
                              hipStream_t stream) {
    const float* X  = (const float*)d_in[0];
    const int* mask = (const int*)d_in[1];
    const float* Wq = (const float*)d_in[2];
    const float* bq = (const float*)d_in[3];
    const float* Wk = (const float*)d_in[4];
    const float* bk = (const float*)d_in[5];
    const float* Wv = (const float*)d_in[6];
    const float* bv = (const float*)d_in[7];
    float* out = (float*)d_out;
    float* partials = (float*)d_ws;

    const int B = in_sizes[0] / (SEQ * DIM);

    // Largest T (t-chunks) whose partial buffer fits in the workspace.
    int T = 16;
    while (T > 1 && (size_t)B * T * SEQ * 8 * sizeof(float) > ws_size) T >>= 1;
    const int chunk = SEQ / T;

    const size_t shmem = (size_t)chunk * 8 * sizeof(__fp16) * 2;  // K + Vp

    dim3 grid1(SEQ / (BLOCK * RROWS), T, B);
    attn_partial<<<grid1, BLOCK, shmem, stream>>>(X, mask, Wq, bq, Wk, bk, Wv, bv,
                                                  partials, T, chunk);

    dim3 grid2((B * SEQ) / BLOCK);
    attn_reduce<<<grid2, BLOCK, 0, stream>>>(partials, out, T);
}

// Round 7
// 32.424 us; speedup vs baseline: 2.0877x; 2.0877x over previous
//
#include <hip/hip_runtime.h>

#define SEQ 2048
#define DIM 6
#define NW 8                 // waves per block
#define BLOCK (NW * 64)
#define VROW 2056            // padded V^T row stride in halves (2048 + 8)

typedef _Float16 half4F __attribute__((ext_vector_type(4)));
typedef float f32x4 __attribute__((ext_vector_type(4)));

union FragU { uint2 u; half4F h; };

__device__ __forceinline__ unsigned pkh(float a, float b) {
    return __builtin_bit_cast(unsigned, __builtin_amdgcn_cvt_pkrtz(a, b));
}

// K' [t][8] fp16: {k0..k5 (x log2e), bias (0 / -1024), 1.0}
// Vt [7][VROW] fp16: rows 0..5 = V dims (transposed), row 6 = ones (denominator)
// QK MFMA: A=K'-tile, B=Q' -> D[t_loc][s] = log2e*score + bias - m (phase 2)
// PV MFMA: A=exp2(D) (lane-local relayout!), B=Vt-tile -> C[s'][d], col6 = denom

__launch_bounds__(BLOCK, 4)
__global__ void attn_mfma(const float* __restrict__ X,
                          const int* __restrict__ mask,
                          const float* __restrict__ Wq, const float* __restrict__ bq,
                          const float* __restrict__ Wk, const float* __restrict__ bk,
                          const float* __restrict__ Wv, const float* __restrict__ bv,
                          float* __restrict__ out) {
    __shared__ __align__(16) __fp16 Ksm[SEQ * 8];
    __shared__ __align__(16) __fp16 Vtsm[7 * VROW];

    const int b = blockIdx.x >> 4;   // 16 blocks per batch
    const int tid = threadIdx.x;
    const float* Xb = X + (size_t)b * SEQ * DIM;
    const int* mb = mask + (size_t)b * SEQ;
    const float L2E = 1.44269504088896f;

    // ---- Stage K' and V^T for this batch ----
#pragma unroll
    for (int i = 0; i < SEQ / BLOCK; ++i) {
        const int t = tid + i * BLOCK;
        const float2* xp = reinterpret_cast<const float2*>(Xb + t * DIM);
        float2 x01 = xp[0], x23 = xp[1], x45 = xp[2];
        float x[DIM] = {x01.x, x01.y, x23.x, x23.y, x45.x, x45.y};
        float kk[DIM], vv[DIM];
#pragma unroll
        for (int r = 0; r < DIM; ++r) {
            float k = bk[r], v = bv[r];
#pragma unroll
            for (int c = 0; c < DIM; ++c) {
                k = fmaf(Wk[r * DIM + c], x[c], k);
                v = fmaf(Wv[r * DIM + c], x[c], v);
            }
            kk[r] = k * L2E;
            vv[r] = v;
        }
        const float bias = (mb[t] == 0) ? -1024.0f : 0.0f;
        uint4 kw;
        kw.x = pkh(kk[0], kk[1]);
        kw.y = pkh(kk[2], kk[3]);
        kw.z = pkh(kk[4], kk[5]);
        kw.w = pkh(bias, 1.0f);
        *reinterpret_cast<uint4*>(&Ksm[t * 8]) = kw;
#pragma unroll
        for (int r = 0; r < DIM; ++r) Vtsm[r * VROW + t] = (__fp16)vv[r];
        Vtsm[6 * VROW + t] = (__fp16)1.0f;
    }
    __syncthreads();

    // ---- Per-wave: one 16-row s-tile ----
    const int lane = tid & 63, wid = tid >> 6;
    const int s0 = ((blockIdx.x & 15) * NW + wid) * 16;
    const int r15 = lane & 15, g = lane >> 4;
    const int s = s0 + r15;

    // Q' projection for row s (4 lane-copies compute the same row)
    float qq[DIM], biasm;
    {
        const float2* xp = reinterpret_cast<const float2*>(Xb + s * DIM);
        float2 x01 = xp[0], x23 = xp[1], x45 = xp[2];
        float x[DIM] = {x01.x, x01.y, x23.x, x23.y, x45.x, x45.y};
        const bool rm = (mb[s] == 0);  // masked row -> p=1 over all t
#pragma unroll
        for (int r = 0; r < DIM; ++r) {
            float q = bq[r];
#pragma unroll
            for (int c = 0; c < DIM; ++c) q = fmaf(Wq[r * DIM + c], x[c], q);
            qq[r] = rm ? 0.0f : q;
        }
        biasm = rm ? 0.0f : 1.0f;
    }

    // B-fragment (phase 1, offset slot = 0): lane holds Q'[s][g*4 .. g*4+3]
    FragU qf1;
    qf1.u.x = (g == 0) ? pkh(qq[0], qq[1]) : (g == 1) ? pkh(qq[4], qq[5]) : 0u;
    qf1.u.y = (g == 0) ? pkh(qq[2], qq[3]) : (g == 1) ? pkh(biasm, 0.0f) : 0u;

    const f32x4 zero4 = {0.0f, 0.0f, 0.0f, 0.0f};

    // ---- Phase 1: per-row max of arg = L2E*score + bias ----
    float m0 = -1024.f, m1 = -1024.f, m2 = -1024.f, m3 = -1024.f;
    {
        int kidx = r15 * 8 + (g & 1) * 4;
#pragma unroll 4
        for (int tt = 0; tt < SEQ / 16; ++tt) {
            half4F kf = *reinterpret_cast<const half4F*>(&Ksm[kidx]);
            f32x4 d = __builtin_amdgcn_mfma_f32_16x16x16f16(kf, qf1.h, zero4, 0, 0, 0);
            m0 = fmaxf(m0, d[0]);
            m1 = fmaxf(m1, d[1]);
            m2 = fmaxf(m2, d[2]);
            m3 = fmaxf(m3, d[3]);
            kidx += 128;
        }
    }
    float mm = fmaxf(fmaxf(m0, m1), fmaxf(m2, m3));
    mm = fmaxf(mm, __shfl_xor(mm, 16));
    mm = fmaxf(mm, __shfl_xor(mm, 32));  // row max for column s, lane-replicated

    FragU qf2 = qf1;
    if (g == 1) qf2.u.y = pkh(biasm, -mm);  // offset slot: K'[t][7]=1 * (-m_s)

    // ---- Phase 2: P = exp2(arg - m) <= ~1 (fp16-safe); O/denom via PV MFMA ----
    f32x4 acc = zero4;
    {
        const int dcl = (r15 < 6) ? r15 : 6;  // cols 7..15 read ones row (ignored)
        int kidx = r15 * 8 + (g & 1) * 4;
        int vidx = dcl * VROW + g * 4;
#pragma unroll 2
        for (int tt = 0; tt < SEQ / 16; ++tt) {
            half4F kf = *reinterpret_cast<const half4F*>(&Ksm[kidx]);
            f32x4 d = __builtin_amdgcn_mfma_f32_16x16x16f16(kf, qf2.h, zero4, 0, 0, 0);
            FragU pa;  // P in PV A-layout: same lane, same (s, t_loc) mapping
            pa.u.x = pkh(__builtin_amdgcn_exp2f(d[0]), __builtin_amdgcn_exp2f(d[1]));
            pa.u.y = pkh(__builtin_amdgcn_exp2f(d[2]), __builtin_amdgcn_exp2f(d[3]));
            half4F vf = *reinterpret_cast<const half4F*>(&Vtsm[vidx]);
            acc = __builtin_amdgcn_mfma_f32_16x16x16f16(pa.h, vf, acc, 0, 0, 0);
            kidx += 128;
            vidx += 16;
        }
    }

    // ---- Epilogue: divide numerators (cols 0..5) by denominator (col 6) ----
    const int srcl = (lane & 48) | 6;
#pragma unroll
    for (int r = 0; r < 4; ++r) {
        const float dnm = __shfl(acc[r], srcl);
        const float val = acc[r] * __builtin_amdgcn_rcpf(dnm);
        if (r15 < 6) {
            out[((size_t)b * SEQ + s0 + g * 4 + r) * DIM + r15] = val;
        }
    }
}

extern "C" void kernel_launch(void* const* d_in, const int* in_sizes, int n_in,
                              void* d_out, int out_size, void* d_ws, size_t ws_size,
                              hipStream_t stream) {
    const float* X  = (const float*)d_in[0];
    const int* mask = (const int*)d_in[1];
    const float* Wq = (const float*)d_in[2];
    const float* bq = (const float*)d_in[3];
    const float* Wk = (const float*)d_in[4];
    const float* bk = (const float*)d_in[5];
    const float* Wv = (const float*)d_in[6];
    const float* bv = (const float*)d_in[7];
    float* out = (float*)d_out;

    const int B = in_sizes[0] / (SEQ * DIM);

    dim3 grid(B * 16);  // 16 blocks per batch, 8 s-tiles (waves) per block
    attn_mfma<<<grid, BLOCK, 0, stream>>>(X, mask, Wq, bq, Wk, bk, Wv, bv, out);
}